// Round 1
// 378.091 us; speedup vs baseline: 1.0140x; 1.0140x over previous
//
#include <hip/hip_runtime.h>

// AttentionBiasHead: B=32, L=512, DIM_IN=512, DQ=DK=128, DS=256, DMLP=128
// Round 8: attn_mfma8 — 8-wave blocks (2 waves/SIMD), key-split across 2 wave
// groups, register-prefetch double-buffering for K/V/bias staging, LDS-staged
// bias, reg-resident Q, LDS O-combine + vectorized f32 output, XCD-aware block
// decode. Mask dtype resolved host-side from in_sizes (runtime detect = fallback).
// proj_mfma / wtrans / mlp1 / bias_mlp2 unchanged (proven).

typedef unsigned int   u32;
typedef unsigned short u16;
typedef __attribute__((ext_vector_type(8))) short bf16x8;   // 8 bf16 = 4 VGPR
typedef __attribute__((ext_vector_type(4))) float f32x4;
typedef __attribute__((ext_vector_type(4))) u32   u32x4;    // 16B = 8 u16

__device__ __forceinline__ float B2F(u16 x) { return __uint_as_float(((u32)x) << 16); }
__device__ __forceinline__ u16 f2bf(float f) {
    u32 u = __float_as_uint(f);
    return (u16)((u + 0x7fffu + ((u >> 16) & 1u)) >> 16);   // RNE
}

// ---------------------------------------------------------------------------
// Mask dtype detector + canonicalizer (fallback path only).
// ---------------------------------------------------------------------------
__global__ __launch_bounds__(256) void mask_detect(const u32* __restrict__ m,
                                                   u32* __restrict__ flag)
{
    const size_t t = (size_t)blockIdx.x * 256 + threadIdx.x;   // grid 2048
    u32 any = 0;
#pragma unroll
    for (int l = 0; l < 4; ++l) any |= (m[t * 4 + l] > 1u) ? 1u : 0u;
    if (__ballot(any)) {
        if ((threadIdx.x & 63) == 0) atomicOr(flag, 1u);
    }
}

__global__ __launch_bounds__(256) void mask_canon(const void* __restrict__ mask,
                                                  const u32* __restrict__ flag,
                                                  unsigned char* __restrict__ canon)
{
    const size_t i = (size_t)blockIdx.x * 256 + threadIdx.x;   // grid 32768
    if (*flag == 0) canon[i] = (((const int*)mask)[i] != 0) ? 1 : 0;
    else            canon[i] = (((const unsigned char*)mask)[i] != 0) ? 1 : 0;
}

// Fast path: dtype known from in_sizes (i32 -> bytes).
__global__ __launch_bounds__(256) void mask_canon_i32(const int* __restrict__ m,
                                                      unsigned char* __restrict__ canon)
{
    const size_t i = (size_t)blockIdx.x * 256 + threadIdx.x;   // grid 32768
    canon[i] = (m[i] != 0) ? 1 : 0;
}

// ---------------------------------------------------------------------------
// W transpose + bf16 convert: WT[s][n=128][k=512] <- W_s[k][n] f32.
// ---------------------------------------------------------------------------
__global__ __launch_bounds__(256) void wtrans(
    const float* __restrict__ Wq, const float* __restrict__ Wk, const float* __restrict__ Wv,
    u16* __restrict__ WT)
{
    const float* W = (blockIdx.y == 0) ? Wq : (blockIdx.y == 1) ? Wk : Wv;
    __shared__ u16 Ts[64][136];
    const int tid = threadIdx.x, kt = blockIdx.x;

    {
        const int kk = tid >> 2, nseg = tid & 3;
        const float4* src = (const float4*)(W + (size_t)(kt * 64 + kk) * 128 + nseg * 32);
#pragma unroll
        for (int j = 0; j < 8; ++j) {
            float4 v = src[j];
            Ts[kk][nseg * 32 + j * 4 + 0] = f2bf(v.x);
            Ts[kk][nseg * 32 + j * 4 + 1] = f2bf(v.y);
            Ts[kk][nseg * 32 + j * 4 + 2] = f2bf(v.z);
            Ts[kk][nseg * 32 + j * 4 + 3] = f2bf(v.w);
        }
    }
    __syncthreads();
    {
        const int n = tid >> 1, kseg = tid & 1;
        u32 pk[16];
#pragma unroll
        for (int j = 0; j < 16; ++j)
            pk[j] = (u32)Ts[kseg * 32 + 2 * j][n] | ((u32)Ts[kseg * 32 + 2 * j + 1][n] << 16);
        u32x4* dst = (u32x4*)(WT + (size_t)blockIdx.y * 65536 + (size_t)n * 512 + kt * 64 + kseg * 32);
        dst[0] = (u32x4){pk[0], pk[1], pk[2], pk[3]};
        dst[1] = (u32x4){pk[4], pk[5], pk[6], pk[7]};
        dst[2] = (u32x4){pk[8], pk[9], pk[10], pk[11]};
        dst[3] = (u32x4){pk[12], pk[13], pk[14], pk[15]};
    }
}

// ---------------------------------------------------------------------------
// MFMA QKV projection (unchanged).
// ---------------------------------------------------------------------------
__global__ __launch_bounds__(256) void proj_mfma(
    const float* __restrict__ Xq, const float* __restrict__ Xk, const float* __restrict__ Xv,
    const u16* __restrict__ WT,
    const float* __restrict__ Bq, const float* __restrict__ Bk, const float* __restrict__ Bv,
    u16* __restrict__ Yq, u16* __restrict__ Yk, u16* __restrict__ YvT)
{
    const int s = blockIdx.y;
    const float* X; const float* Bi;
    if (s == 0)      { X = Xq; Bi = Bq; }
    else if (s == 1) { X = Xk; Bi = Bk; }
    else             { X = Xv; Bi = Bv; }
    const u16* Wn = WT + (size_t)s * 65536;

    __shared__ u16 Xs[64][72];
    __shared__ u16 Ws[128][72];

    const int tid  = threadIdx.x;
    const int w    = tid >> 6;
    const int lane = tid & 63;
    const int c    = lane & 15;
    const int qd   = lane >> 4;
    const int R0   = blockIdx.x * 64;

    f32x4 acc[8];
#pragma unroll
    for (int t = 0; t < 8; ++t) acc[t] = (f32x4){0.f, 0.f, 0.f, 0.f};

    for (int kc = 0; kc < 8; ++kc) {
        __syncthreads();
        {
            const int row = tid >> 2, seg = tid & 3;
            const float4* src = (const float4*)(X + (size_t)(R0 + row) * 512 + kc * 64 + seg * 16);
            float4 v0 = src[0], v1 = src[1], v2 = src[2], v3 = src[3];
            u32 pk[8];
            pk[0] = (u32)f2bf(v0.x) | ((u32)f2bf(v0.y) << 16);
            pk[1] = (u32)f2bf(v0.z) | ((u32)f2bf(v0.w) << 16);
            pk[2] = (u32)f2bf(v1.x) | ((u32)f2bf(v1.y) << 16);
            pk[3] = (u32)f2bf(v1.z) | ((u32)f2bf(v1.w) << 16);
            pk[4] = (u32)f2bf(v2.x) | ((u32)f2bf(v2.y) << 16);
            pk[5] = (u32)f2bf(v2.z) | ((u32)f2bf(v2.w) << 16);
            pk[6] = (u32)f2bf(v3.x) | ((u32)f2bf(v3.y) << 16);
            pk[7] = (u32)f2bf(v3.z) | ((u32)f2bf(v3.w) << 16);
            u32x4* dst = (u32x4*)&Xs[row][seg * 16];
            dst[0] = (u32x4){pk[0], pk[1], pk[2], pk[3]};
            dst[1] = (u32x4){pk[4], pk[5], pk[6], pk[7]};
        }
        {
            const int n = tid >> 1, seg = tid & 1;
            const u32x4* src = (const u32x4*)(Wn + (size_t)n * 512 + kc * 64 + seg * 32);
            u32x4 v0 = src[0], v1 = src[1], v2 = src[2], v3 = src[3];
            u32x4* dst = (u32x4*)&Ws[n][seg * 32];
            dst[0] = v0; dst[1] = v1; dst[2] = v2; dst[3] = v3;
        }
        __syncthreads();

#pragma unroll
        for (int ks = 0; ks < 2; ++ks) {
            if (s < 2) {
                const bf16x8 a = *(const bf16x8*)&Xs[w * 16 + c][ks * 32 + qd * 8];
#pragma unroll
                for (int nt = 0; nt < 8; ++nt) {
                    const bf16x8 b = *(const bf16x8*)&Ws[nt * 16 + c][ks * 32 + qd * 8];
                    acc[nt] = __builtin_amdgcn_mfma_f32_16x16x32_bf16(a, b, acc[nt], 0, 0, 0);
                }
            } else {
#pragma unroll
                for (int t = 0; t < 2; ++t) {
                    const bf16x8 a = *(const bf16x8*)&Ws[(2 * w + t) * 16 + c][ks * 32 + qd * 8];
#pragma unroll
                    for (int it = 0; it < 4; ++it) {
                        const bf16x8 b = *(const bf16x8*)&Xs[it * 16 + c][ks * 32 + qd * 8];
                        acc[t * 4 + it] = __builtin_amdgcn_mfma_f32_16x16x32_bf16(a, b, acc[t * 4 + it], 0, 0, 0);
                    }
                }
            }
        }
    }

    if (s < 2) {
        u16* Y = (s == 0) ? Yq : Yk;
#pragma unroll
        for (int nt = 0; nt < 8; ++nt) {
            const float bn = Bi[nt * 16 + c];
#pragma unroll
            for (int r = 0; r < 4; ++r)
                Y[(size_t)(R0 + w * 16 + qd * 4 + r) * 128 + nt * 16 + c] = f2bf(acc[nt][r] + bn);
        }
    } else {
        const int bb = blockIdx.x >> 3, il0 = R0 & 511;
#pragma unroll
        for (int t = 0; t < 2; ++t)
#pragma unroll
            for (int r = 0; r < 4; ++r) {
                const int d = (2 * w + t) * 16 + qd * 4 + r;
                const float bd = Bi[d];
#pragma unroll
                for (int it = 0; it < 4; ++it)
                    YvT[(size_t)bb * 65536 + (size_t)d * 512 + il0 + it * 16 + c] =
                        f2bf(acc[t * 4 + it][r] + bd);
            }
    }
}

// ---------------------------------------------------------------------------
// h = relu(sf @ Wb1 + bb1)  (unchanged)
// ---------------------------------------------------------------------------
__global__ __launch_bounds__(256) void mlp1_kernel(
    const float* __restrict__ sf, const float* __restrict__ Wb1,
    const float* __restrict__ bb1, float* __restrict__ h)
{
    const int t = blockIdx.x * 256 + threadIdx.x;   // grid 16
    const int b = t >> 7, n = t & 127;
    float acc = bb1[n];
    for (int m = 0; m < 256; ++m)
        acc += sf[b * 256 + m] * Wb1[m * 128 + n];
    h[t] = fmaxf(acc, 0.0f);
}

// ---------------------------------------------------------------------------
// bias = h @ Wb2 + bb2 -> bf16 (unchanged; Wb2 128 MB streamed once).
// ---------------------------------------------------------------------------
__global__ __launch_bounds__(256) void bias_mlp2(
    const float* __restrict__ h, const float* __restrict__ Wb2,
    const float* __restrict__ bb2, u16* __restrict__ biasb)
{
    __shared__ float hs[4096];
    const int tid = threadIdx.x;
#pragma unroll
    for (int l = 0; l < 16; ++l) hs[l * 256 + tid] = h[l * 256 + tid];
    __syncthreads();

    const size_t n = (size_t)blockIdx.x * 256 + tid;   // grid 1024
    float acc[32];
    const float bb = bb2[n];
#pragma unroll
    for (int b = 0; b < 32; ++b) acc[b] = bb;

    for (int m4 = 0; m4 < 32; ++m4) {
        const float w0 = Wb2[(size_t)(m4 * 4 + 0) * 262144 + n];
        const float w1 = Wb2[(size_t)(m4 * 4 + 1) * 262144 + n];
        const float w2 = Wb2[(size_t)(m4 * 4 + 2) * 262144 + n];
        const float w3 = Wb2[(size_t)(m4 * 4 + 3) * 262144 + n];
#pragma unroll
        for (int b = 0; b < 32; ++b) {
            const float4 hv = *(const float4*)&hs[b * 128 + m4 * 4];
            acc[b] += hv.x * w0 + hv.y * w1 + hv.z * w2 + hv.w * w3;
        }
    }
#pragma unroll
    for (int b = 0; b < 32; ++b)
        biasb[(size_t)b * 262144 + n] = f2bf(acc[b]);
}

// ---------------------------------------------------------------------------
// attn_mfma8: 512 threads = 8 waves; group g = keys [g*256, g*256+256).
// 2 waves/SIMD; reg-prefetch double-buffering; LDS bias; LDS O-combine.
// Block decode: bb = blk&31, it = blk>>5  => blocks sharing a batch's K/V
// land on the same XCD (round-robin dispatch assumption; perf-only).
// ---------------------------------------------------------------------------
__global__ __launch_bounds__(512, 2) void attn_mfma8(
    const u16* __restrict__ qb, const u16* __restrict__ kb, const u16* __restrict__ vTb,
    const unsigned char* __restrict__ canon, const u16* __restrict__ biasb,
    float* __restrict__ out)
{
    __shared__ alignas(16) u16 Ks[2][64 * 136];   // 34816 B (reused as Oc later)
    __shared__ alignas(16) u16 Ps[2][64 * 72];    // 18432 B
    __shared__ alignas(16) u16 Vs[2][128 * 72];   // 36864 B
    __shared__ alignas(16) u16 Bs[2][64 * 72];    // 18432 B
    __shared__ float redm[2][64];
    __shared__ float reds[2][64];
    // total ~107 KiB

    const int tid  = threadIdx.x;
    const int g    = tid >> 8;          // wave group 0/1
    const int gtid = tid & 255;
    const int wl   = (tid >> 6) & 3;    // wave within group
    const int lane = tid & 63;
    const int c    = lane & 15;
    const int qd   = lane >> 4;
    const int bb   = blockIdx.x & 31;   // XCD-coherent decode
    const int it   = blockIdx.x >> 5;
    const int i0   = it * 64;

    // ---- Q fragments direct to registers -------------------------------
    bf16x8 qf[4];
    {
        const u16* qp = qb + ((size_t)bb * 512 + i0 + wl * 16 + c) * 128 + qd * 8;
#pragma unroll
        for (int kc = 0; kc < 4; ++kc) qf[kc] = *(const bf16x8*)(qp + kc * 32);
    }

    // ---- QK^T over this group's 4 key tiles ----------------------------
    const int kr_ = gtid >> 2, ksg = gtid & 3;
    const u16* kbase = kb + ((size_t)bb * 512 + g * 256) * 128;
    {   // stage tile 0
        const u32x4* src = (const u32x4*)(kbase + (size_t)kr_ * 128 + ksg * 32);
        u32x4 k0 = src[0], k1 = src[1], k2 = src[2], k3 = src[3];
        u32x4* dst = (u32x4*)&Ks[g][kr_ * 136 + ksg * 32];
        dst[0] = k0; dst[1] = k1; dst[2] = k2; dst[3] = k3;
    }
    __syncthreads();

    f32x4 S[4][4];
#pragma unroll
    for (int jt = 0; jt < 4; ++jt)
#pragma unroll
        for (int jj = 0; jj < 4; ++jj) S[jt][jj] = (f32x4){0.f, 0.f, 0.f, 0.f};

#pragma unroll
    for (int jt = 0; jt < 4; ++jt) {
        u32x4 k0, k1, k2, k3;
        if (jt < 3) {   // prefetch next tile into regs; latency hides under MFMA
            const u32x4* src = (const u32x4*)(kbase + ((size_t)(jt + 1) * 64 + kr_) * 128 + ksg * 32);
            k0 = src[0]; k1 = src[1]; k2 = src[2]; k3 = src[3];
        }
#pragma unroll
        for (int kc = 0; kc < 4; ++kc) {
            const bf16x8 a = qf[kc];
#pragma unroll
            for (int jj = 0; jj < 4; ++jj) {
                const bf16x8 b = *(const bf16x8*)&Ks[g][(jj * 16 + c) * 136 + kc * 32 + qd * 8];
                S[jt][jj] = __builtin_amdgcn_mfma_f32_16x16x32_bf16(a, b, S[jt][jj], 0, 0, 0);
            }
        }
        if (jt < 3) {
            __syncthreads();
            u32x4* dst = (u32x4*)&Ks[g][kr_ * 136 + ksg * 32];
            dst[0] = k0; dst[1] = k1; dst[2] = k2; dst[3] = k3;
            __syncthreads();
        }
    }

    // ---- prefetch V/bias tile 0 (latency hides under softmax) ----------
    const int vd = gtid >> 1, vsg = gtid & 1;
    const int brw = gtid >> 2, bsg = gtid & 3;
    const u16* vbase = vTb + (size_t)bb * 65536;
    const u16* bbase = biasb + (size_t)bb * 262144;
    u32x4 vr0, vr1, vr2, vr3, br0, br1;
    {
        const u32x4* sv = (const u32x4*)(vbase + (size_t)vd * 512 + (g * 4) * 64 + vsg * 32);
        vr0 = sv[0]; vr1 = sv[1]; vr2 = sv[2]; vr3 = sv[3];
        const u32x4* sb = (const u32x4*)(bbase + (size_t)(i0 + brw) * 512 + (g * 4) * 64 + bsg * 16);
        br0 = sb[0]; br1 = sb[1];
    }

    // ---- softmax: group-local then cross-group combine -----------------
    const float sc = 0.08838834764831845f;
    float lm[4];
#pragma unroll
    for (int r = 0; r < 4; ++r) {
        const int lrow = wl * 16 + qd * 4 + r;
        const unsigned char* cp = canon + ((size_t)bb * 512 + i0 + lrow) * 512 + g * 256;
        float mx = -3.4e38f;
#pragma unroll
        for (int jt = 0; jt < 4; ++jt)
#pragma unroll
            for (int jj = 0; jj < 4; ++jj) {
                float s = S[jt][jj][r] * sc;
                if (cp[jt * 64 + jj * 16 + c]) s = 1e-9f;
                S[jt][jj][r] = s;
                mx = fmaxf(mx, s);
            }
#pragma unroll
        for (int o = 1; o < 16; o <<= 1) mx = fmaxf(mx, __shfl_xor(mx, o, 64));
        lm[r] = mx;
    }
    if (c == 0) {
#pragma unroll
        for (int r = 0; r < 4; ++r) redm[g][wl * 16 + qd * 4 + r] = lm[r];
    }
    __syncthreads();
    float ls[4];
#pragma unroll
    for (int r = 0; r < 4; ++r) {
        const int lrow = wl * 16 + qd * 4 + r;
        const float gmx = fmaxf(redm[0][lrow], redm[1][lrow]);
        float sm = 0.f;
#pragma unroll
        for (int jt = 0; jt < 4; ++jt)
#pragma unroll
            for (int jj = 0; jj < 4; ++jj) {
                const float e = __expf(S[jt][jj][r] - gmx);
                S[jt][jj][r] = e;
                sm += e;
            }
#pragma unroll
        for (int o = 1; o < 16; o <<= 1) sm += __shfl_xor(sm, o, 64);
        ls[r] = sm;
    }
    if (c == 0) {
#pragma unroll
        for (int r = 0; r < 4; ++r) reds[g][wl * 16 + qd * 4 + r] = ls[r];
    }
    __syncthreads();
    float inv_[4];
#pragma unroll
    for (int r = 0; r < 4; ++r) {
        const int lrow = wl * 16 + qd * 4 + r;
        inv_[r] = 1.0f / (reds[0][lrow] + reds[1][lrow]);
    }

    // ---- PV over this group's 4 key tiles ------------------------------
    f32x4 O_[8];
#pragma unroll
    for (int ns = 0; ns < 8; ++ns) O_[ns] = (f32x4){0.f, 0.f, 0.f, 0.f};

#pragma unroll
    for (int jt = 0; jt < 4; ++jt) {
        __syncthreads();   // all waves past MFMA(jt-1) reads of Vs/Ps
        {
            u32x4* dv = (u32x4*)&Vs[g][vd * 72 + vsg * 32];
            dv[0] = vr0; dv[1] = vr1; dv[2] = vr2; dv[3] = vr3;
            u32x4* db = (u32x4*)&Bs[g][brw * 72 + bsg * 16];
            db[0] = br0; db[1] = br1;
        }
        __syncthreads();   // Vs/Bs visible
        if (jt < 3) {      // prefetch next tile; hides under P-write + MFMA
            const int tg = g * 4 + jt + 1;
            const u32x4* sv = (const u32x4*)(vbase + (size_t)vd * 512 + tg * 64 + vsg * 32);
            vr0 = sv[0]; vr1 = sv[1]; vr2 = sv[2]; vr3 = sv[3];
            const u32x4* sb = (const u32x4*)(bbase + (size_t)(i0 + brw) * 512 + tg * 64 + bsg * 16);
            br0 = sb[0]; br1 = sb[1];
        }
#pragma unroll
        for (int r = 0; r < 4; ++r) {
            const int lrow = wl * 16 + qd * 4 + r;
#pragma unroll
            for (int jj = 0; jj < 4; ++jj) {
                const float p = S[jt][jj][r] * inv_[r] + B2F(Bs[g][lrow * 72 + jj * 16 + c]);
                Ps[g][lrow * 72 + jj * 16 + c] = f2bf(p);
            }
        }
        __syncthreads();   // Ps visible
#pragma unroll
        for (int kc = 0; kc < 2; ++kc) {
            const bf16x8 a = *(const bf16x8*)&Ps[g][(wl * 16 + c) * 72 + kc * 32 + qd * 8];
#pragma unroll
            for (int ns = 0; ns < 8; ++ns) {
                const bf16x8 b = *(const bf16x8*)&Vs[g][(ns * 16 + c) * 72 + kc * 32 + qd * 8];
                O_[ns] = __builtin_amdgcn_mfma_f32_16x16x32_bf16(a, b, O_[ns], 0, 0, 0);
            }
        }
    }

    // ---- cross-group O combine (reuse dead Ks space) + coalesced store -
    __syncthreads();
    float* Oc = (float*)&Ks[0][0];   // 32 KiB
    if (g == 1) {
#pragma unroll
        for (int ns = 0; ns < 8; ++ns)
#pragma unroll
            for (int r = 0; r < 4; ++r)
                Oc[(wl * 16 + qd * 4 + r) * 128 + ns * 16 + c] = O_[ns][r];
    }
    __syncthreads();
    if (g == 0) {
#pragma unroll
        for (int ns = 0; ns < 8; ++ns)
#pragma unroll
            for (int r = 0; r < 4; ++r)
                Oc[(wl * 16 + qd * 4 + r) * 128 + ns * 16 + c] += O_[ns][r];
    }
    __syncthreads();
    {
        const int row = tid >> 3, sg = tid & 7;
        const float4* s4 = (const float4*)&Oc[row * 128 + sg * 16];
        float4* d4 = (float4*)(out + ((size_t)bb * 512 + i0 + row) * 128 + sg * 16);
        d4[0] = s4[0]; d4[1] = s4[1]; d4[2] = s4[2]; d4[3] = s4[3];
    }
}

// ---------------------------------------------------------------------------
extern "C" void kernel_launch(void* const* d_in, const int* in_sizes, int n_in,
                              void* d_out, int out_size, void* d_ws, size_t ws_size,
                              hipStream_t stream)
{
    const float* query = (const float*)d_in[0];
    const float* key_  = (const float*)d_in[1];
    const float* value = (const float*)d_in[2];
    const float* sf    = (const float*)d_in[3];
    const void*  mask  = d_in[4];
    const float* Wq  = (const float*)d_in[5];
    const float* bq  = (const float*)d_in[6];
    const float* Wk  = (const float*)d_in[7];
    const float* bk  = (const float*)d_in[8];
    const float* Wv  = (const float*)d_in[9];
    const float* bv  = (const float*)d_in[10];
    const float* Wb1 = (const float*)d_in[11];
    const float* bb1 = (const float*)d_in[12];
    const float* Wb2 = (const float*)d_in[13];
    const float* bb2 = (const float*)d_in[14];
    float* out = (float*)d_out;

    // ws layout
    char* w = (char*)d_ws;
    u32*   flag     = (u32*)(w);                                // 4 B
    unsigned char* canonbuf = (unsigned char*)(w + (1u << 20)); // 8 MiB
    u16*   qb    = (u16*)(w + (16u << 20));                     // 4 MiB
    u16*   kb    = (u16*)(w + (24u << 20));                     // 4 MiB
    u16*   vTb   = (u16*)(w + (32u << 20));                     // 4 MiB
    float* h     = (float*)(w + (40u << 20));                   // 16 KiB
    u16*   biasb = (u16*)(w + (41u << 20));                     // 16 MiB
    u16*   WT    = (u16*)(w + (58u << 20));                     // 384 KiB

    // Mask dtype from in_sizes (bytes convention confirmed via query size).
    // bool mask: 32*512*512 = 8388608 B -> use buffer directly (values 0/1).
    // i32 mask : 33554432 B -> one convert kernel. Anything else: runtime detect.
    const unsigned char* canon;
    const bool bytes_conv = (n_in >= 15 && in_sizes[0] == 33554432);
    if (bytes_conv && in_sizes[4] == 8388608) {
        canon = (const unsigned char*)mask;
    } else if (bytes_conv && in_sizes[4] == 33554432) {
        mask_canon_i32<<<32768, 256, 0, stream>>>((const int*)mask, canonbuf);
        canon = canonbuf;
    } else {
        hipMemsetAsync(flag, 0, 4, stream);
        mask_detect<<<2048, 256, 0, stream>>>((const u32*)mask, flag);
        mask_canon<<<32768, 256, 0, stream>>>(mask, flag, canonbuf);
        canon = canonbuf;
    }

    wtrans<<<dim3(8, 3), 256, 0, stream>>>(Wq, Wk, Wv, WT);
    proj_mfma<<<dim3(256, 3), 256, 0, stream>>>(query, key_, value, WT,
                                                bq, bk, bv, qb, kb, vTb);
    mlp1_kernel<<<16, 256, 0, stream>>>(sf, Wb1, bb1, h);
    bias_mlp2<<<1024, 256, 0, stream>>>(h, Wb2, bb2, biasb);
    attn_mfma8<<<256, 512, 0, stream>>>(qb, kb, vTb, canon, biasb, out);
}

// Round 2
// 345.246 us; speedup vs baseline: 1.1104x; 1.0951x over previous
//
#include <hip/hip_runtime.h>

// AttentionBiasHead: B=32, L=512, DIM_IN=512, DQ=DK=128, DS=256, DMLP=128
// Round 9: 3-dispatch pipeline.
//   prep = mask_detect + wtrans + mlp1(->hT transposed)     [independent work]
//   mid  = bias_mlp2(SGPR-broadcast h, no LDS) + proj_mfma + mask_canon
//   attn = attn_mfma8 (unchanged from round 8)
// bias_mlp2 redesign: hT[m][b] uniform loads -> SGPR broadcast (kills the
// per-(m,b) LDS-broadcast bottleneck); thread = 2 n (float2) x 32 b.
// Mask dtype: mode resolved host-side when unambiguous, else runtime flag.

typedef unsigned int   u32;
typedef unsigned short u16;
typedef __attribute__((ext_vector_type(8))) short bf16x8;   // 8 bf16 = 4 VGPR
typedef __attribute__((ext_vector_type(4))) float f32x4;
typedef __attribute__((ext_vector_type(4))) u32   u32x4;    // 16B = 8 u16

__device__ __forceinline__ float B2F(u16 x) { return __uint_as_float(((u32)x) << 16); }
__device__ __forceinline__ u16 f2bf(float f) {
    u32 u = __float_as_uint(f);
    return (u16)((u + 0x7fffu + ((u >> 16) & 1u)) >> 16);   // RNE
}

// ---------------------------------------------------------------------------
// prep: [0,detN) mask_detect | [detN,detN+24) wtrans | [detN+24,detN+40) mlp1
// ---------------------------------------------------------------------------
__global__ __launch_bounds__(256) void prep(
    const void* __restrict__ mask, u32* __restrict__ flag, int detN,
    const float* __restrict__ Wq, const float* __restrict__ Wk, const float* __restrict__ Wv,
    u16* __restrict__ WT,
    const float* __restrict__ sf, const float* __restrict__ Wb1,
    const float* __restrict__ bb1, float* __restrict__ hT)
{
    __shared__ u16 Ts[64][136];
    const int blk = blockIdx.x, tid = threadIdx.x;

    if (blk < detN) {
        // ---- mask dtype detect: any u32 word > 1 => byte-bool source ----
        const u32* m = (const u32*)mask;
        const size_t t = (size_t)blk * 256 + tid;
        u32 any = 0;
#pragma unroll
        for (int l = 0; l < 4; ++l) any |= (m[t * 4 + l] > 1u) ? 1u : 0u;
        if (__ballot(any)) {
            if ((tid & 63) == 0) atomicOr(flag, 1u);
        }
        return;
    }
    if (blk < detN + 24) {
        // ---- wtrans: WT[s][n=128][k=512] <- W_s[k][n] f32 ----
        const int widx = blk - detN;
        const int s = widx >> 3, kt = widx & 7;
        const float* W = (s == 0) ? Wq : (s == 1) ? Wk : Wv;
        {
            const int kk = tid >> 2, nseg = tid & 3;
            const float4* src = (const float4*)(W + (size_t)(kt * 64 + kk) * 128 + nseg * 32);
#pragma unroll
            for (int j = 0; j < 8; ++j) {
                float4 v = src[j];
                Ts[kk][nseg * 32 + j * 4 + 0] = f2bf(v.x);
                Ts[kk][nseg * 32 + j * 4 + 1] = f2bf(v.y);
                Ts[kk][nseg * 32 + j * 4 + 2] = f2bf(v.z);
                Ts[kk][nseg * 32 + j * 4 + 3] = f2bf(v.w);
            }
        }
        __syncthreads();
        {
            const int n = tid >> 1, kseg = tid & 1;
            u32 pk[16];
#pragma unroll
            for (int j = 0; j < 16; ++j)
                pk[j] = (u32)Ts[kseg * 32 + 2 * j][n] | ((u32)Ts[kseg * 32 + 2 * j + 1][n] << 16);
            u32x4* dst = (u32x4*)(WT + (size_t)s * 65536 + (size_t)n * 512 + kt * 64 + kseg * 32);
            dst[0] = (u32x4){pk[0], pk[1], pk[2], pk[3]};
            dst[1] = (u32x4){pk[4], pk[5], pk[6], pk[7]};
            dst[2] = (u32x4){pk[8], pk[9], pk[10], pk[11]};
            dst[3] = (u32x4){pk[12], pk[13], pk[14], pk[15]};
        }
        return;
    }
    {
        // ---- mlp1: hT[n][b] = relu(sf @ Wb1 + bb1), transposed store ----
        const int t = (blk - detN - 24) * 256 + tid;   // 16 blocks -> 4096
        const int b = t >> 7, n = t & 127;
        float acc = bb1[n];
        for (int m = 0; m < 256; ++m)
            acc += sf[b * 256 + m] * Wb1[m * 128 + n];
        hT[n * 32 + b] = fmaxf(acc, 0.0f);
    }
}

// ---------------------------------------------------------------------------
// mid: [0,512) bias2 | [512,1280) proj_mfma | [1280,1280+canN) mask_canon
// ---------------------------------------------------------------------------
__global__ __launch_bounds__(256) void mid(
    const float* __restrict__ Xq, const float* __restrict__ Xk, const float* __restrict__ Xv,
    const u16* __restrict__ WT,
    const float* __restrict__ Bq, const float* __restrict__ Bk, const float* __restrict__ Bv,
    u16* __restrict__ Yq, u16* __restrict__ Yk, u16* __restrict__ YvT,
    const float* __restrict__ hT, const float* __restrict__ Wb2,
    const float* __restrict__ bb2, u16* __restrict__ biasb,
    const void* __restrict__ mask, const u32* __restrict__ flag, int mode,
    unsigned char* __restrict__ canonbuf)
{
    __shared__ u16 Xs[64][72];
    __shared__ u16 Ws[128][72];
    const int blk = blockIdx.x, tid = threadIdx.x;

    if (blk < 512) {
        // ---- bias = hT^T @ Wb2 + bb2 -> bf16. h broadcast via SGPR. ----
        const size_t n0 = ((size_t)blk * 256 + tid) * 2;
        float ax[32], ay[32];
        {
            const float2 bb = *(const float2*)&bb2[n0];
#pragma unroll
            for (int b = 0; b < 32; ++b) { ax[b] = bb.x; ay[b] = bb.y; }
        }
#pragma unroll 2
        for (int m = 0; m < 128; ++m) {
            const float2 w2 = *(const float2*)&Wb2[(size_t)m * 262144 + n0];
            const float* hrow = hT + m * 32;     // wave-uniform -> s_load
#pragma unroll
            for (int b = 0; b < 32; ++b) {
                const float hv = hrow[b];
                ax[b] += w2.x * hv;
                ay[b] += w2.y * hv;
            }
        }
#pragma unroll
        for (int b = 0; b < 32; ++b) {
            const u32 pk = (u32)f2bf(ax[b]) | ((u32)f2bf(ay[b]) << 16);
            *(u32*)(biasb + (size_t)b * 262144 + n0) = pk;
        }
        return;
    }

    if (blk < 1280) {
        // ---- proj_mfma (round-8 body) ----
        const int pidx = blk - 512;
        const int s = pidx >> 8;
        const int R0 = (pidx & 255) * 64;
        const float* X; const float* Bi;
        if (s == 0)      { X = Xq; Bi = Bq; }
        else if (s == 1) { X = Xk; Bi = Bk; }
        else             { X = Xv; Bi = Bv; }
        const u16* Wn = WT + (size_t)s * 65536;

        const int w    = tid >> 6;
        const int lane = tid & 63;
        const int c    = lane & 15;
        const int qd   = lane >> 4;

        f32x4 acc[8];
#pragma unroll
        for (int t = 0; t < 8; ++t) acc[t] = (f32x4){0.f, 0.f, 0.f, 0.f};

        for (int kc = 0; kc < 8; ++kc) {
            __syncthreads();
            {
                const int row = tid >> 2, seg = tid & 3;
                const float4* src = (const float4*)(X + (size_t)(R0 + row) * 512 + kc * 64 + seg * 16);
                float4 v0 = src[0], v1 = src[1], v2 = src[2], v3 = src[3];
                u32 pk[8];
                pk[0] = (u32)f2bf(v0.x) | ((u32)f2bf(v0.y) << 16);
                pk[1] = (u32)f2bf(v0.z) | ((u32)f2bf(v0.w) << 16);
                pk[2] = (u32)f2bf(v1.x) | ((u32)f2bf(v1.y) << 16);
                pk[3] = (u32)f2bf(v1.z) | ((u32)f2bf(v1.w) << 16);
                pk[4] = (u32)f2bf(v2.x) | ((u32)f2bf(v2.y) << 16);
                pk[5] = (u32)f2bf(v2.z) | ((u32)f2bf(v2.w) << 16);
                pk[6] = (u32)f2bf(v3.x) | ((u32)f2bf(v3.y) << 16);
                pk[7] = (u32)f2bf(v3.z) | ((u32)f2bf(v3.w) << 16);
                u32x4* dst = (u32x4*)&Xs[row][seg * 16];
                dst[0] = (u32x4){pk[0], pk[1], pk[2], pk[3]};
                dst[1] = (u32x4){pk[4], pk[5], pk[6], pk[7]};
            }
            {
                const int n = tid >> 1, seg = tid & 1;
                const u32x4* src = (const u32x4*)(Wn + (size_t)n * 512 + kc * 64 + seg * 32);
                u32x4 v0 = src[0], v1 = src[1], v2 = src[2], v3 = src[3];
                u32x4* dst = (u32x4*)&Ws[n][seg * 32];
                dst[0] = v0; dst[1] = v1; dst[2] = v2; dst[3] = v3;
            }
            __syncthreads();

#pragma unroll
            for (int ks = 0; ks < 2; ++ks) {
                if (s < 2) {
                    const bf16x8 a = *(const bf16x8*)&Xs[w * 16 + c][ks * 32 + qd * 8];
#pragma unroll
                    for (int nt = 0; nt < 8; ++nt) {
                        const bf16x8 b = *(const bf16x8*)&Ws[nt * 16 + c][ks * 32 + qd * 8];
                        acc[nt] = __builtin_amdgcn_mfma_f32_16x16x32_bf16(a, b, acc[nt], 0, 0, 0);
                    }
                } else {
#pragma unroll
                    for (int t = 0; t < 2; ++t) {
                        const bf16x8 a = *(const bf16x8*)&Ws[(2 * w + t) * 16 + c][ks * 32 + qd * 8];
#pragma unroll
                        for (int it = 0; it < 4; ++it) {
                            const bf16x8 b = *(const bf16x8*)&Xs[it * 16 + c][ks * 32 + qd * 8];
                            acc[t * 4 + it] = __builtin_amdgcn_mfma_f32_16x16x32_bf16(a, b, acc[t * 4 + it], 0, 0, 0);
                        }
                    }
                }
            }
        }

        if (s < 2) {
            u16* Y = (s == 0) ? Yq : Yk;
#pragma unroll
            for (int nt = 0; nt < 8; ++nt) {
                const float bn = Bi[nt * 16 + c];
#pragma unroll
                for (int r = 0; r < 4; ++r)
                    Y[(size_t)(R0 + w * 16 + qd * 4 + r) * 128 + nt * 16 + c] = f2bf(acc[nt][r] + bn);
            }
        } else {
            const int bb = (pidx & 255) >> 3, il0 = R0 & 511;
#pragma unroll
            for (int t = 0; t < 2; ++t)
#pragma unroll
                for (int r = 0; r < 4; ++r) {
                    const int d = (2 * w + t) * 16 + qd * 4 + r;
                    const float bd = Bi[d];
#pragma unroll
                    for (int it = 0; it < 4; ++it)
                        YvT[(size_t)bb * 65536 + (size_t)d * 512 + il0 + it * 16 + c] =
                            f2bf(acc[t * 4 + it][r] + bd);
                }
        }
        return;
    }

    {
        // ---- mask_canon: 2048 blocks x 256 thr x 16 elems, coalesced ----
        const int cb = blk - 1280;
        const size_t base = (size_t)cb * 4096;
        const bool i32src = (mode == 2) || (mode == 0 && *flag == 0);
        if (i32src) {
            const int* mi = (const int*)mask;
#pragma unroll
            for (int j = 0; j < 16; ++j) {
                const size_t i = base + (size_t)j * 256 + tid;
                canonbuf[i] = mi[i] ? 1 : 0;
            }
        } else {
            const unsigned char* mb = (const unsigned char*)mask;
#pragma unroll
            for (int j = 0; j < 16; ++j) {
                const size_t i = base + (size_t)j * 256 + tid;
                canonbuf[i] = mb[i] ? 1 : 0;
            }
        }
    }
}

// ---------------------------------------------------------------------------
// attn_mfma8 (unchanged, round 8): 8 waves, key-split 2 groups, reg-prefetch.
// ---------------------------------------------------------------------------
__global__ __launch_bounds__(512, 2) void attn_mfma8(
    const u16* __restrict__ qb, const u16* __restrict__ kb, const u16* __restrict__ vTb,
    const unsigned char* __restrict__ canon, const u16* __restrict__ biasb,
    float* __restrict__ out)
{
    __shared__ alignas(16) u16 Ks[2][64 * 136];
    __shared__ alignas(16) u16 Ps[2][64 * 72];
    __shared__ alignas(16) u16 Vs[2][128 * 72];
    __shared__ alignas(16) u16 Bs[2][64 * 72];
    __shared__ float redm[2][64];
    __shared__ float reds[2][64];

    const int tid  = threadIdx.x;
    const int g    = tid >> 8;
    const int gtid = tid & 255;
    const int wl   = (tid >> 6) & 3;
    const int lane = tid & 63;
    const int c    = lane & 15;
    const int qd   = lane >> 4;
    const int bb   = blockIdx.x & 31;
    const int it   = blockIdx.x >> 5;
    const int i0   = it * 64;

    bf16x8 qf[4];
    {
        const u16* qp = qb + ((size_t)bb * 512 + i0 + wl * 16 + c) * 128 + qd * 8;
#pragma unroll
        for (int kc = 0; kc < 4; ++kc) qf[kc] = *(const bf16x8*)(qp + kc * 32);
    }

    const int kr_ = gtid >> 2, ksg = gtid & 3;
    const u16* kbase = kb + ((size_t)bb * 512 + g * 256) * 128;
    {
        const u32x4* src = (const u32x4*)(kbase + (size_t)kr_ * 128 + ksg * 32);
        u32x4 k0 = src[0], k1 = src[1], k2 = src[2], k3 = src[3];
        u32x4* dst = (u32x4*)&Ks[g][kr_ * 136 + ksg * 32];
        dst[0] = k0; dst[1] = k1; dst[2] = k2; dst[3] = k3;
    }
    __syncthreads();

    f32x4 S[4][4];
#pragma unroll
    for (int jt = 0; jt < 4; ++jt)
#pragma unroll
        for (int jj = 0; jj < 4; ++jj) S[jt][jj] = (f32x4){0.f, 0.f, 0.f, 0.f};

#pragma unroll
    for (int jt = 0; jt < 4; ++jt) {
        u32x4 k0, k1, k2, k3;
        if (jt < 3) {
            const u32x4* src = (const u32x4*)(kbase + ((size_t)(jt + 1) * 64 + kr_) * 128 + ksg * 32);
            k0 = src[0]; k1 = src[1]; k2 = src[2]; k3 = src[3];
        }
#pragma unroll
        for (int kc = 0; kc < 4; ++kc) {
            const bf16x8 a = qf[kc];
#pragma unroll
            for (int jj = 0; jj < 4; ++jj) {
                const bf16x8 b = *(const bf16x8*)&Ks[g][(jj * 16 + c) * 136 + kc * 32 + qd * 8];
                S[jt][jj] = __builtin_amdgcn_mfma_f32_16x16x32_bf16(a, b, S[jt][jj], 0, 0, 0);
            }
        }
        if (jt < 3) {
            __syncthreads();
            u32x4* dst = (u32x4*)&Ks[g][kr_ * 136 + ksg * 32];
            dst[0] = k0; dst[1] = k1; dst[2] = k2; dst[3] = k3;
            __syncthreads();
        }
    }

    const int vd = gtid >> 1, vsg = gtid & 1;
    const int brw = gtid >> 2, bsg = gtid & 3;
    const u16* vbase = vTb + (size_t)bb * 65536;
    const u16* bbase = biasb + (size_t)bb * 262144;
    u32x4 vr0, vr1, vr2, vr3, br0, br1;
    {
        const u32x4* sv = (const u32x4*)(vbase + (size_t)vd * 512 + (g * 4) * 64 + vsg * 32);
        vr0 = sv[0]; vr1 = sv[1]; vr2 = sv[2]; vr3 = sv[3];
        const u32x4* sb = (const u32x4*)(bbase + (size_t)(i0 + brw) * 512 + (g * 4) * 64 + bsg * 16);
        br0 = sb[0]; br1 = sb[1];
    }

    const float sc = 0.08838834764831845f;
    float lm[4];
#pragma unroll
    for (int r = 0; r < 4; ++r) {
        const int lrow = wl * 16 + qd * 4 + r;
        const unsigned char* cp = canon + ((size_t)bb * 512 + i0 + lrow) * 512 + g * 256;
        float mx = -3.4e38f;
#pragma unroll
        for (int jt = 0; jt < 4; ++jt)
#pragma unroll
            for (int jj = 0; jj < 4; ++jj) {
                float s = S[jt][jj][r] * sc;
                if (cp[jt * 64 + jj * 16 + c]) s = 1e-9f;
                S[jt][jj][r] = s;
                mx = fmaxf(mx, s);
            }
#pragma unroll
        for (int o = 1; o < 16; o <<= 1) mx = fmaxf(mx, __shfl_xor(mx, o, 64));
        lm[r] = mx;
    }
    if (c == 0) {
#pragma unroll
        for (int r = 0; r < 4; ++r) redm[g][wl * 16 + qd * 4 + r] = lm[r];
    }
    __syncthreads();
    float ls[4];
#pragma unroll
    for (int r = 0; r < 4; ++r) {
        const int lrow = wl * 16 + qd * 4 + r;
        const float gmx = fmaxf(redm[0][lrow], redm[1][lrow]);
        float sm = 0.f;
#pragma unroll
        for (int jt = 0; jt < 4; ++jt)
#pragma unroll
            for (int jj = 0; jj < 4; ++jj) {
                const float e = __expf(S[jt][jj][r] - gmx);
                S[jt][jj][r] = e;
                sm += e;
            }
#pragma unroll
        for (int o = 1; o < 16; o <<= 1) sm += __shfl_xor(sm, o, 64);
        ls[r] = sm;
    }
    if (c == 0) {
#pragma unroll
        for (int r = 0; r < 4; ++r) reds[g][wl * 16 + qd * 4 + r] = ls[r];
    }
    __syncthreads();
    float inv_[4];
#pragma unroll
    for (int r = 0; r < 4; ++r) {
        const int lrow = wl * 16 + qd * 4 + r;
        inv_[r] = 1.0f / (reds[0][lrow] + reds[1][lrow]);
    }

    f32x4 O_[8];
#pragma unroll
    for (int ns = 0; ns < 8; ++ns) O_[ns] = (f32x4){0.f, 0.f, 0.f, 0.f};

#pragma unroll
    for (int jt = 0; jt < 4; ++jt) {
        __syncthreads();
        {
            u32x4* dv = (u32x4*)&Vs[g][vd * 72 + vsg * 32];
            dv[0] = vr0; dv[1] = vr1; dv[2] = vr2; dv[3] = vr3;
            u32x4* db = (u32x4*)&Bs[g][brw * 72 + bsg * 16];
            db[0] = br0; db[1] = br1;
        }
        __syncthreads();
        if (jt < 3) {
            const int tg = g * 4 + jt + 1;
            const u32x4* sv = (const u32x4*)(vbase + (size_t)vd * 512 + tg * 64 + vsg * 32);
            vr0 = sv[0]; vr1 = sv[1]; vr2 = sv[2]; vr3 = sv[3];
            const u32x4* sb = (const u32x4*)(bbase + (size_t)(i0 + brw) * 512 + tg * 64 + bsg * 16);
            br0 = sb[0]; br1 = sb[1];
        }
#pragma unroll
        for (int r = 0; r < 4; ++r) {
            const int lrow = wl * 16 + qd * 4 + r;
#pragma unroll
            for (int jj = 0; jj < 4; ++jj) {
                const float p = S[jt][jj][r] * inv_[r] + B2F(Bs[g][lrow * 72 + jj * 16 + c]);
                Ps[g][lrow * 72 + jj * 16 + c] = f2bf(p);
            }
        }
        __syncthreads();
#pragma unroll
        for (int kc = 0; kc < 2; ++kc) {
            const bf16x8 a = *(const bf16x8*)&Ps[g][(wl * 16 + c) * 72 + kc * 32 + qd * 8];
#pragma unroll
            for (int ns = 0; ns < 8; ++ns) {
                const bf16x8 b = *(const bf16x8*)&Vs[g][(ns * 16 + c) * 72 + kc * 32 + qd * 8];
                O_[ns] = __builtin_amdgcn_mfma_f32_16x16x32_bf16(a, b, O_[ns], 0, 0, 0);
            }
        }
    }

    __syncthreads();
    float* Oc = (float*)&Ks[0][0];
    if (g == 1) {
#pragma unroll
        for (int ns = 0; ns < 8; ++ns)
#pragma unroll
            for (int r = 0; r < 4; ++r)
                Oc[(wl * 16 + qd * 4 + r) * 128 + ns * 16 + c] = O_[ns][r];
    }
    __syncthreads();
    if (g == 0) {
#pragma unroll
        for (int ns = 0; ns < 8; ++ns)
#pragma unroll
            for (int r = 0; r < 4; ++r)
                Oc[(wl * 16 + qd * 4 + r) * 128 + ns * 16 + c] += O_[ns][r];
    }
    __syncthreads();
    {
        const int row = tid >> 3, sg = tid & 7;
        const float4* s4 = (const float4*)&Oc[row * 128 + sg * 16];
        float4* d4 = (float4*)(out + ((size_t)bb * 512 + i0 + row) * 128 + sg * 16);
        d4[0] = s4[0]; d4[1] = s4[1]; d4[2] = s4[2]; d4[3] = s4[3];
    }
}

// ---------------------------------------------------------------------------
extern "C" void kernel_launch(void* const* d_in, const int* in_sizes, int n_in,
                              void* d_out, int out_size, void* d_ws, size_t ws_size,
                              hipStream_t stream)
{
    const float* query = (const float*)d_in[0];
    const float* key_  = (const float*)d_in[1];
    const float* value = (const float*)d_in[2];
    const float* sf    = (const float*)d_in[3];
    const void*  mask  = d_in[4];
    const float* Wq  = (const float*)d_in[5];
    const float* bq  = (const float*)d_in[6];
    const float* Wk  = (const float*)d_in[7];
    const float* bk  = (const float*)d_in[8];
    const float* Wv  = (const float*)d_in[9];
    const float* bv  = (const float*)d_in[10];
    const float* Wb1 = (const float*)d_in[11];
    const float* bb1 = (const float*)d_in[12];
    const float* Wb2 = (const float*)d_in[13];
    const float* bb2 = (const float*)d_in[14];
    float* out = (float*)d_out;

    // ws layout
    char* w = (char*)d_ws;
    u32*   flag     = (u32*)(w);                                // 4 B
    unsigned char* canonbuf = (unsigned char*)(w + (1u << 20)); // 8 MiB
    u16*   qb    = (u16*)(w + (16u << 20));                     // 4 MiB
    u16*   kb    = (u16*)(w + (24u << 20));                     // 4 MiB
    u16*   vTb   = (u16*)(w + (32u << 20));                     // 4 MiB
    float* hT    = (float*)(w + (40u << 20));                   // 16 KiB (hT[m][b])
    u16*   biasb = (u16*)(w + (41u << 20));                     // 16 MiB
    u16*   WT    = (u16*)(w + (58u << 20));                     // 384 KiB

    // Mask dtype: mode 0 = runtime detect, 1 = bool bytes direct, 2 = i32.
    // Only trust in_sizes when they are unambiguously BYTE counts (query =
    // 32*512*512*4 = 33554432 B). Element-count convention falls to mode 0.
    int mode = 0;
    if (n_in >= 15 && in_sizes[0] == 33554432) {
        if (in_sizes[4] == 8388608)       mode = 1;
        else if (in_sizes[4] == 33554432) mode = 2;
    }
    if (mode == 0) hipMemsetAsync(flag, 0, 4, stream);

    const int detN = (mode == 0) ? 2048 : 0;
    prep<<<detN + 40, 256, 0, stream>>>(mask, flag, detN, Wq, Wk, Wv, WT,
                                        sf, Wb1, bb1, hT);

    const int canN = (mode != 1) ? 2048 : 0;
    mid<<<1280 + canN, 256, 0, stream>>>(query, key_, value, WT,
                                         bq, bk, bv, qb, kb, vTb,
                                         hT, Wb2, bb2, biasb,
                                         mask, flag, mode, canonbuf);

    const unsigned char* canon = (mode == 1) ? (const unsigned char*)mask : canonbuf;
    attn_mfma8<<<256, 512, 0, stream>>>(qb, kb, vTb, canon, biasb, out);
}